// Round 12
// baseline (6109.528 us; speedup 1.0000x reference)
//
#include <hip/hip_runtime.h>
#include <hip/hip_fp16.h>
#include <cstdint>
#include <cstddef>

#define DIM 128
#define BN_EPS_ 1e-5f

typedef _Float16 half8 __attribute__((ext_vector_type(8)));
typedef float floatx4 __attribute__((ext_vector_type(4)));

#define SCALE_H 32768.f
#define INV_H   (1.f/32768.f)

__device__ __forceinline__ float fast_tanh(float x) {
    float t = __expf(2.f * x);
    return 1.f - 2.f / (t + 1.f);
}

__device__ __forceinline__ short quant(float v, float scale) {
    int q = __float2int_rn(v * scale);
    q = max(min(q, 32767), -32767);
    return (short)q;
}

// ---------------- BN stats: per-feature sum/sumsq/maxabs of h' = x*imp ----------------
__global__ __launch_bounds__(256) void k_stats(
    const float* __restrict__ x, const float* __restrict__ imp,
    float* __restrict__ gsum, float* __restrict__ gsq, float* __restrict__ gmax, int N)
{
    __shared__ float ls[256], lq[256], lm[256];
    int t = threadIdx.x;
    int f = t & 127;
    int rs = t >> 7;
    float s = 0.f, q = 0.f, m = 0.f;
    for (int r = blockIdx.x * 2 + rs; r < N; r += gridDim.x * 2) {
        float v = x[(size_t)r * DIM + f] * imp[r];
        s += v; q += v * v; m = fmaxf(m, fabsf(v));
    }
    ls[t] = s; lq[t] = q; lm[t] = m;
    __syncthreads();
    if (t < 128) {
        atomicAdd(&gsum[f], ls[t] + ls[t + 128]);
        atomicAdd(&gsq[f],  lq[t] + lq[t + 128]);
        float mm = fmaxf(lm[t], lm[t + 128]);
        atomicMax((int*)&gmax[f], __float_as_int(mm));  // valid: mm >= 0
    }
}

__global__ void k_finalize(const float* __restrict__ gsum, const float* __restrict__ gsq,
                           const float* __restrict__ gmax,
                           const float* __restrict__ gamma, const float* __restrict__ beta,
                           float* __restrict__ scale, float* __restrict__ shift,
                           float* __restrict__ q0, int N)
{
    __shared__ float sb[128];
    int f = threadIdx.x;
    float mean = gsum[f] / (float)N;
    float var  = gsq[f] / (float)N - mean * mean;
    var = fmaxf(var, 0.f);
    float sc = gamma[f] * rsqrtf(var + BN_EPS_);
    float sh = beta[f] - mean * sc;
    scale[f] = sc;
    shift[f] = sh;
    sb[f] = fabsf(sc) * gmax[f] + fabsf(sh);
    __syncthreads();
    for (int off = 64; off > 0; off >>= 1) {
        if (f < off) sb[f] = fmaxf(sb[f], sb[f + off]);
        __syncthreads();
    }
    if (f == 0) {
        float Q = fmaxf(sb[0], 1e-20f);
        q0[0] = 32766.f / Q;
        q0[1] = Q / 32766.f;
    }
}

__global__ __launch_bounds__(256) void k_bn_quant(
    const float* __restrict__ x, const float* __restrict__ imp,
    const float* __restrict__ scale, const float* __restrict__ shift,
    const float* __restrict__ q0, short* __restrict__ hq0, int n32)
{
    int i = blockIdx.x * 256 + threadIdx.x;
    if (i >= n32) return;
    float qs = q0[0];
    int r = i >> 5, f4 = i & 31;
    float im = imp[r];
    float4 v  = ((const float4*)x)[i];
    float4 sc = ((const float4*)scale)[f4];
    float4 sh = ((const float4*)shift)[f4];
    short q[4];
    q[0] = quant(fmaf(v.x * im, sc.x, sh.x), qs);
    q[1] = quant(fmaf(v.y * im, sc.y, sh.y), qs);
    q[2] = quant(fmaf(v.z * im, sc.z, sh.z), qs);
    q[3] = quant(fmaf(v.w * im, sc.w, sh.w), qs);
    *(float2*)(hq0 + (size_t)i * 4) = *(float2*)q;
}

// ---------------- weight split: Wt{Hi,Lo}[n][k] from f32 W[k][n] ----------------
__global__ __launch_bounds__(256) void k_wsplit(const float* __restrict__ W,
                                               _Float16* __restrict__ WtHi,
                                               _Float16* __restrict__ WtLo)
{
    for (int e = blockIdx.x * 256 + threadIdx.x; e < DIM * DIM; e += gridDim.x * 256) {
        int k = e >> 7, n = e & 127;
        float w = W[e];
        _Float16 hi = (_Float16)w;
        _Float16 lo = (_Float16)(w - (float)hi);
        WtHi[n * DIM + k] = hi;
        WtLo[n * DIM + k] = lo;
    }
}

// ---------------- CSC build (group edges by SOURCE, payload = dst) ----------------
__global__ void k_hist(const int* __restrict__ key, int* __restrict__ deg, int E)
{
    int e = blockIdx.x * 256 + threadIdx.x;
    if (e < E) atomicAdd(&deg[key[e]], 1);
}

__global__ __launch_bounds__(256) void k_chunksum(const int* __restrict__ deg, int* __restrict__ csum, int N)
{
    __shared__ int s[256];
    int t = threadIdx.x;
    int i = blockIdx.x * 256 + t;
    s[t] = (i < N) ? deg[i] : 0;
    __syncthreads();
    for (int off = 128; off > 0; off >>= 1) {
        if (t < off) s[t] += s[t + off];
        __syncthreads();
    }
    if (t == 0) csum[blockIdx.x] = s[0];
}

__global__ void k_scanchunks(int* __restrict__ csum, int* __restrict__ rstart, int nchunks, int N)
{
    __shared__ int s[512];
    int t = threadIdx.x;
    s[t] = (t < nchunks) ? csum[t] : 0;
    __syncthreads();
    for (int off = 1; off < 512; off <<= 1) {
        int add = (t >= off) ? s[t - off] : 0;
        __syncthreads();
        s[t] += add;
        __syncthreads();
    }
    if (t < nchunks) csum[t] = (t > 0) ? s[t - 1] : 0;
    if (t == 511) rstart[N] = s[511];
}

__global__ __launch_bounds__(256) void k_scanwithin(
    const int* __restrict__ deg, const int* __restrict__ csum,
    int* __restrict__ rstart, int* __restrict__ cursor, int N)
{
    __shared__ int s[256];
    int t = threadIdx.x;
    int i = blockIdx.x * 256 + t;
    int v = (i < N) ? deg[i] : 0;
    s[t] = v;
    __syncthreads();
    for (int off = 1; off < 256; off <<= 1) {
        int add = (t >= off) ? s[t - off] : 0;
        __syncthreads();
        s[t] += add;
        __syncthreads();
    }
    if (i < N) {
        int rs = csum[blockIdx.x] + s[t] - v;
        rstart[i] = rs;
        cursor[i] = rs;
    }
}

// group by key[e], store payload[e]
__global__ void k_scatter(const int* __restrict__ payload, const int* __restrict__ key,
                          int* __restrict__ cursor, int* __restrict__ csc, int E)
{
    int e = blockIdx.x * 256 + threadIdx.x;
    if (e < E) {
        int k = key[e];
        int pos = atomicAdd(&cursor[k], 1);
        csc[pos] = payload[e];
    }
}

// ---------------- push aggregation: S[dst] += hq[src] (int32 atomics, exact) ------------
// One wave per source batch; source row read ONCE, coalesced (4B/lane).
// Atomic adds are non-returning -> fire-and-forget, no read-miss latency chain.
__global__ __launch_bounds__(256) void k_push(
    const short* __restrict__ hq,
    const int* __restrict__ cstart, const int* __restrict__ csc,
    int* __restrict__ S, int N)
{
    int wv = threadIdx.x >> 6;
    int lane = threadIdx.x & 63;
    int s0 = blockIdx.x * 32 + wv * 8;
    for (int i = 0; i < 8; ++i) {
        int s = s0 + i;
        if (s >= N) return;
        unsigned row = *(const unsigned*)(hq + (size_t)s * DIM + lane * 2);
        int v0 = (int)(short)(row & 0xffffu);
        int v1 = (int)(short)(row >> 16);
        int beg = __builtin_amdgcn_readfirstlane(cstart[s]);
        int end = __builtin_amdgcn_readfirstlane(cstart[s + 1]);
        // self contribution (GIN: h_i + sum_j h_j)
        int* sp = S + (size_t)s * DIM + lane * 2;
        atomicAdd(sp, v0);
        atomicAdd(sp + 1, v1);
        int e = beg;
        for (; e + 4 <= end; e += 4) {
            int d0 = csc[e], d1 = csc[e + 1], d2 = csc[e + 2], d3 = csc[e + 3];
            int* p0 = S + (size_t)d0 * DIM + lane * 2;
            int* p1 = S + (size_t)d1 * DIM + lane * 2;
            int* p2 = S + (size_t)d2 * DIM + lane * 2;
            int* p3 = S + (size_t)d3 * DIM + lane * 2;
            atomicAdd(p0, v0); atomicAdd(p0 + 1, v1);
            atomicAdd(p1, v0); atomicAdd(p1 + 1, v1);
            atomicAdd(p2, v0); atomicAdd(p2 + 1, v1);
            atomicAdd(p3, v0); atomicAdd(p3 + 1, v1);
        }
        for (; e < end; ++e) {
            int d0 = csc[e];
            int* p0 = S + (size_t)d0 * DIM + lane * 2;
            atomicAdd(p0, v0); atomicAdd(p0 + 1, v1);
        }
    }
}

// ---------------- MFMA GEMM: t = tanh((S*inv) @ W + b) ----------------
// block 256 = 4 waves, 64 rows. Reads int32 S; hi/lo fp16 split in-register.
// Writes out slice (nt-store) + optional int16 hq for next layer.
// FINAL=1: loops the h5 tile through LDS and applies Wfc fused.
template<int FINAL>
__global__ __launch_bounds__(256) void k_gemmQ(
    const int* __restrict__ S,
    const float* __restrict__ invPtr, float invConst,
    const _Float16* __restrict__ WtHi, const _Float16* __restrict__ WtLo,
    const float* __restrict__ bias,
    const _Float16* __restrict__ WfHi, const _Float16* __restrict__ WfLo,
    float* __restrict__ outS,          // out + l*128, ld 768
    float* __restrict__ outF,          // out + 5*128 (FINAL only)
    short* __restrict__ hqNext,        // may be null
    int N)
{
    int t = threadIdx.x;
    float inv = invPtr ? invPtr[0] : invConst;
    int wave = t >> 6;
    int lane = t & 63;
    int r0 = blockIdx.x * 64 + wave * 16;
    int arow = r0 + (lane & 15);
    if (arow >= N) arow = N - 1;
    int kg = (lane >> 4) * 8;

    half8 ahi[4], alo[4];
#pragma unroll
    for (int ks = 0; ks < 4; ++ks) {
        const int* ap = S + (size_t)arow * DIM + ks * 32 + kg;
        int4 i0 = *(const int4*)ap;
        int4 i1 = *(const int4*)(ap + 4);
        float fv[8] = {i0.x * inv, i0.y * inv, i0.z * inv, i0.w * inv,
                       i1.x * inv, i1.y * inv, i1.z * inv, i1.w * inv};
#pragma unroll
        for (int j = 0; j < 8; ++j) {
            _Float16 h = (_Float16)fv[j];
            ahi[ks][j] = h;
            alo[ks][j] = (_Float16)(fv[j] - (float)h);
        }
    }

    floatx4 acc[8];
#pragma unroll
    for (int nt = 0; nt < 8; ++nt) acc[nt] = (floatx4){0.f, 0.f, 0.f, 0.f};
#pragma unroll
    for (int nt = 0; nt < 8; ++nt) {
        int ncol = nt * 16 + (lane & 15);
#pragma unroll
        for (int ks = 0; ks < 4; ++ks) {
            half8 bhi = *(const half8*)(WtHi + (size_t)ncol * DIM + ks * 32 + kg);
            half8 blo = *(const half8*)(WtLo + (size_t)ncol * DIM + ks * 32 + kg);
            acc[nt] = __builtin_amdgcn_mfma_f32_16x16x32_f16(ahi[ks], bhi, acc[nt], 0, 0, 0);
            acc[nt] = __builtin_amdgcn_mfma_f32_16x16x32_f16(alo[ks], bhi, acc[nt], 0, 0, 0);
            acc[nt] = __builtin_amdgcn_mfma_f32_16x16x32_f16(ahi[ks], blo, acc[nt], 0, 0, 0);
        }
    }

    int rbase = r0 + (lane >> 4) * 4;
    float tv[8][4];
#pragma unroll
    for (int nt = 0; nt < 8; ++nt) {
        int col = nt * 16 + (lane & 15);
        float bv = bias ? bias[col] : 0.f;
#pragma unroll
        for (int j = 0; j < 4; ++j) {
            float tt = fast_tanh(acc[nt][j] + bv);
            tv[nt][j] = tt;
            int r = rbase + j;
            if (r < N) {
                __builtin_nontemporal_store(tt, &outS[(size_t)r * 768 + col]);
                if (hqNext) hqNext[(size_t)r * DIM + col] = quant(tt, SCALE_H);
            }
        }
    }

    if constexpr (FINAL) {
        __shared__ float sA[64][132];
        __syncthreads();
        int rbaseL = wave * 16 + (lane >> 4) * 4;
#pragma unroll
        for (int nt = 0; nt < 8; ++nt) {
            int col = nt * 16 + (lane & 15);
#pragma unroll
            for (int j = 0; j < 4; ++j)
                sA[rbaseL + j][col] = tv[nt][j];
        }
        __syncthreads();

        int arowL = wave * 16 + (lane & 15);
        half8 chi[4], clo[4];
#pragma unroll
        for (int ks = 0; ks < 4; ++ks) {
            float4 f0 = *(const float4*)&sA[arowL][ks * 32 + kg];
            float4 f1 = *(const float4*)&sA[arowL][ks * 32 + kg + 4];
            float fv[8] = {f0.x, f0.y, f0.z, f0.w, f1.x, f1.y, f1.z, f1.w};
#pragma unroll
            for (int j = 0; j < 8; ++j) {
                _Float16 h = (_Float16)fv[j];
                chi[ks][j] = h;
                clo[ks][j] = (_Float16)(fv[j] - (float)h);
            }
        }
        floatx4 ac2[8];
#pragma unroll
        for (int nt = 0; nt < 8; ++nt) ac2[nt] = (floatx4){0.f, 0.f, 0.f, 0.f};
#pragma unroll
        for (int nt = 0; nt < 8; ++nt) {
            int ncol = nt * 16 + (lane & 15);
#pragma unroll
            for (int ks = 0; ks < 4; ++ks) {
                half8 bhi = *(const half8*)(WfHi + (size_t)ncol * DIM + ks * 32 + kg);
                half8 blo = *(const half8*)(WfLo + (size_t)ncol * DIM + ks * 32 + kg);
                ac2[nt] = __builtin_amdgcn_mfma_f32_16x16x32_f16(chi[ks], bhi, ac2[nt], 0, 0, 0);
                ac2[nt] = __builtin_amdgcn_mfma_f32_16x16x32_f16(clo[ks], bhi, ac2[nt], 0, 0, 0);
                ac2[nt] = __builtin_amdgcn_mfma_f32_16x16x32_f16(chi[ks], blo, ac2[nt], 0, 0, 0);
            }
        }
#pragma unroll
        for (int nt = 0; nt < 8; ++nt) {
            int col = nt * 16 + (lane & 15);
#pragma unroll
            for (int j = 0; j < 4; ++j) {
                int r = rbase + j;
                if (r < N)
                    __builtin_nontemporal_store(fast_tanh(ac2[nt][j]), &outF[(size_t)r * 768 + col]);
            }
        }
    }
}

extern "C" void kernel_launch(void* const* d_in, const int* in_sizes, int n_in,
                              void* d_out, int out_size, void* d_ws, size_t ws_size,
                              hipStream_t stream)
{
    const float* x     = (const float*)d_in[0];
    const float* imp   = (const float*)d_in[1];
    const int*   eidx  = (const int*)d_in[2];
    const float* gamma = (const float*)d_in[3];
    const float* beta  = (const float*)d_in[4];
    const float* Wfc   = (const float*)d_in[5];
    const float* W[5]; const float* B[5];
    for (int i = 0; i < 5; ++i) {
        W[i] = (const float*)d_in[6 + 2 * i];
        B[i] = (const float*)d_in[7 + 2 * i];
    }
    float* out = (float*)d_out;

    const int N = in_sizes[0] / DIM;
    const int E = in_sizes[2] / 2;
    const int* src = eidx;
    const int* dst = eidx + E;

    char* ws = (char*)d_ws;
    size_t off = 0;
    auto alloc = [&](size_t b) -> char* {
        char* p = ws + off;
        off = (off + b + 255) & ~(size_t)255;
        return p;
    };
    short* hqA = (short*)alloc((size_t)N * DIM * 2);
    short* hqB = (short*)alloc((size_t)N * DIM * 2);
    int*   S   = (int*)alloc((size_t)N * DIM * 4);
    _Float16* WtHi[6]; _Float16* WtLo[6];
    for (int i = 0; i < 6; ++i) {
        WtHi[i] = (_Float16*)alloc(DIM * DIM * 2);
        WtLo[i] = (_Float16*)alloc(DIM * DIM * 2);
    }
    int*   deg    = (int*)alloc((size_t)N * 4);
    int*   cstart = (int*)alloc((size_t)(N + 1) * 4);
    int*   cursor = (int*)alloc((size_t)N * 4);
    int*   csc    = (int*)alloc((size_t)E * 4);
    float* gsum   = (float*)alloc(128 * 4);
    float* gsq    = (float*)alloc(128 * 4);
    float* gmax   = (float*)alloc(128 * 4);
    float* scale  = (float*)alloc(128 * 4);
    float* shift  = (float*)alloc(128 * 4);
    float* q0     = (float*)alloc(2 * 4);
    int*   csum   = (int*)alloc(4096 * 4);

    hipMemsetAsync(gsum, 0, 128 * 4, stream);
    hipMemsetAsync(gsq,  0, 128 * 4, stream);
    hipMemsetAsync(gmax, 0, 128 * 4, stream);
    hipMemsetAsync(deg,  0, (size_t)N * 4, stream);

    // BN -> hq0 (int16, dynamic no-clip scale)
    k_stats<<<1024, 256, 0, stream>>>(x, imp, gsum, gsq, gmax, N);
    k_finalize<<<1, 128, 0, stream>>>(gsum, gsq, gmax, gamma, beta, scale, shift, q0, N);
    k_bn_quant<<<(N * 32 + 255) / 256, 256, 0, stream>>>(x, imp, scale, shift, q0, hqA, N * 32);

    // CSC: group edges by SOURCE, payload = dst
    k_hist<<<(E + 255) / 256, 256, 0, stream>>>(src, deg, E);
    int nchunks = (N + 255) / 256;
    k_chunksum<<<nchunks, 256, 0, stream>>>(deg, csum, N);
    k_scanchunks<<<1, 512, 0, stream>>>(csum, cstart, nchunks, N);
    k_scanwithin<<<nchunks, 256, 0, stream>>>(deg, csum, cstart, cursor, N);
    k_scatter<<<(E + 255) / 256, 256, 0, stream>>>(dst, src, cursor, csc, E);

    // weights
    for (int i = 0; i < 5; ++i)
        k_wsplit<<<8, 256, 0, stream>>>(W[i], WtHi[i], WtLo[i]);
    k_wsplit<<<8, 256, 0, stream>>>(Wfc, WtHi[5], WtLo[5]);

    int gPush = (N + 31) / 32;
    int gGemm = (N + 63) / 64;
    short* cur = hqA;
    short* nxt = hqB;
    for (int l = 0; l < 4; ++l) {
        hipMemsetAsync(S, 0, (size_t)N * DIM * 4, stream);
        k_push<<<gPush, 256, 0, stream>>>(cur, cstart, csc, S, N);
        k_gemmQ<0><<<gGemm, 256, 0, stream>>>(S,
            (l == 0) ? (q0 + 1) : nullptr, INV_H,
            WtHi[l], WtLo[l], B[l], nullptr, nullptr,
            out + (size_t)l * DIM, nullptr, nxt, N);
        short* tmp = cur; cur = nxt; nxt = tmp;
    }
    // layer 5 + fused final FC
    hipMemsetAsync(S, 0, (size_t)N * DIM * 4, stream);
    k_push<<<gPush, 256, 0, stream>>>(cur, cstart, csc, S, N);
    k_gemmQ<1><<<gGemm, 256, 0, stream>>>(S,
        nullptr, INV_H,
        WtHi[4], WtLo[4], B[4], WtHi[5], WtLo[5],
        out + (size_t)4 * DIM, out + (size_t)5 * DIM, nullptr, N);
}

// Round 13
// 941.155 us; speedup vs baseline: 6.4915x; 6.4915x over previous
//
#include <hip/hip_runtime.h>
#include <hip/hip_fp16.h>
#include <cstdint>
#include <cstddef>

#define DIM 128
#define BN_EPS_ 1e-5f

typedef _Float16 half8 __attribute__((ext_vector_type(8)));
typedef float floatx4 __attribute__((ext_vector_type(4)));
typedef short shortx8 __attribute__((ext_vector_type(8)));

#define SCALE_H 32768.f
#define INV_H   (1.f/32768.f)

__device__ __forceinline__ float fast_tanh(float x) {
    float t = __expf(2.f * x);
    return 1.f - 2.f / (t + 1.f);
}

__device__ __forceinline__ short quant(float v, float scale) {
    int q = __float2int_rn(v * scale);
    q = max(min(q, 32767), -32767);
    return (short)q;
}

// ---------------- BN stats: per-feature sum/sumsq/maxabs of h' = x*imp ----------------
__global__ __launch_bounds__(256) void k_stats(
    const float* __restrict__ x, const float* __restrict__ imp,
    float* __restrict__ gsum, float* __restrict__ gsq, float* __restrict__ gmax, int N)
{
    __shared__ float ls[256], lq[256], lm[256];
    int t = threadIdx.x;
    int f = t & 127;
    int rs = t >> 7;
    float s = 0.f, q = 0.f, m = 0.f;
    for (int r = blockIdx.x * 2 + rs; r < N; r += gridDim.x * 2) {
        float v = x[(size_t)r * DIM + f] * imp[r];
        s += v; q += v * v; m = fmaxf(m, fabsf(v));
    }
    ls[t] = s; lq[t] = q; lm[t] = m;
    __syncthreads();
    if (t < 128) {
        atomicAdd(&gsum[f], ls[t] + ls[t + 128]);
        atomicAdd(&gsq[f],  lq[t] + lq[t + 128]);
        float mm = fmaxf(lm[t], lm[t + 128]);
        atomicMax((int*)&gmax[f], __float_as_int(mm));  // valid: mm >= 0
    }
}

__global__ void k_finalize(const float* __restrict__ gsum, const float* __restrict__ gsq,
                           const float* __restrict__ gmax,
                           const float* __restrict__ gamma, const float* __restrict__ beta,
                           float* __restrict__ scale, float* __restrict__ shift,
                           float* __restrict__ q0, int N)
{
    __shared__ float sb[128];
    int f = threadIdx.x;
    float mean = gsum[f] / (float)N;
    float var  = gsq[f] / (float)N - mean * mean;
    var = fmaxf(var, 0.f);
    float sc = gamma[f] * rsqrtf(var + BN_EPS_);
    float sh = beta[f] - mean * sc;
    scale[f] = sc;
    shift[f] = sh;
    sb[f] = fabsf(sc) * gmax[f] + fabsf(sh);
    __syncthreads();
    for (int off = 64; off > 0; off >>= 1) {
        if (f < off) sb[f] = fmaxf(sb[f], sb[f + off]);
        __syncthreads();
    }
    if (f == 0) {
        float Q = fmaxf(sb[0], 1e-20f);
        q0[0] = 32766.f / Q;
        q0[1] = Q / 32766.f;
    }
}

__global__ __launch_bounds__(256) void k_bn_quant(
    const float* __restrict__ x, const float* __restrict__ imp,
    const float* __restrict__ scale, const float* __restrict__ shift,
    const float* __restrict__ q0, short* __restrict__ hq0, int n32)
{
    int i = blockIdx.x * 256 + threadIdx.x;
    if (i >= n32) return;
    float qs = q0[0];
    int r = i >> 5, f4 = i & 31;
    float im = imp[r];
    float4 v  = ((const float4*)x)[i];
    float4 sc = ((const float4*)scale)[f4];
    float4 sh = ((const float4*)shift)[f4];
    short q[4];
    q[0] = quant(fmaf(v.x * im, sc.x, sh.x), qs);
    q[1] = quant(fmaf(v.y * im, sc.y, sh.y), qs);
    q[2] = quant(fmaf(v.z * im, sc.z, sh.z), qs);
    q[3] = quant(fmaf(v.w * im, sc.w, sh.w), qs);
    *(float2*)(hq0 + (size_t)i * 4) = *(float2*)q;
}

// ---------------- weight split: Wt{Hi,Lo}[n][k] from f32 W[k][n] ----------------
__global__ __launch_bounds__(256) void k_wsplit(const float* __restrict__ W,
                                               _Float16* __restrict__ WtHi,
                                               _Float16* __restrict__ WtLo)
{
    for (int e = blockIdx.x * 256 + threadIdx.x; e < DIM * DIM; e += gridDim.x * 256) {
        int k = e >> 7, n = e & 127;
        float w = W[e];
        _Float16 hi = (_Float16)w;
        _Float16 lo = (_Float16)(w - (float)hi);
        WtHi[n * DIM + k] = hi;
        WtLo[n * DIM + k] = lo;
    }
}

// ---------------- CSR build ----------------
__global__ void k_hist(const int* __restrict__ dst, int* __restrict__ deg, int E)
{
    int e = blockIdx.x * 256 + threadIdx.x;
    if (e < E) atomicAdd(&deg[dst[e]], 1);
}

__global__ __launch_bounds__(256) void k_chunksum(const int* __restrict__ deg, int* __restrict__ csum, int N)
{
    __shared__ int s[256];
    int t = threadIdx.x;
    int i = blockIdx.x * 256 + t;
    s[t] = (i < N) ? deg[i] : 0;
    __syncthreads();
    for (int off = 128; off > 0; off >>= 1) {
        if (t < off) s[t] += s[t + off];
        __syncthreads();
    }
    if (t == 0) csum[blockIdx.x] = s[0];
}

__global__ void k_scanchunks(int* __restrict__ csum, int* __restrict__ rstart, int nchunks, int N)
{
    __shared__ int s[512];
    int t = threadIdx.x;
    s[t] = (t < nchunks) ? csum[t] : 0;
    __syncthreads();
    for (int off = 1; off < 512; off <<= 1) {
        int add = (t >= off) ? s[t - off] : 0;
        __syncthreads();
        s[t] += add;
        __syncthreads();
    }
    if (t < nchunks) csum[t] = (t > 0) ? s[t - 1] : 0;
    if (t == 511) rstart[N] = s[511];
}

__global__ __launch_bounds__(256) void k_scanwithin(
    const int* __restrict__ deg, const int* __restrict__ csum,
    int* __restrict__ rstart, int* __restrict__ cursor, int N)
{
    __shared__ int s[256];
    int t = threadIdx.x;
    int i = blockIdx.x * 256 + t;
    int v = (i < N) ? deg[i] : 0;
    s[t] = v;
    __syncthreads();
    for (int off = 1; off < 256; off <<= 1) {
        int add = (t >= off) ? s[t - off] : 0;
        __syncthreads();
        s[t] += add;
        __syncthreads();
    }
    if (i < N) {
        int rs = csum[blockIdx.x] + s[t] - v;
        rstart[i] = rs;
        cursor[i] = rs;
    }
}

__global__ void k_scatter(const int* __restrict__ src, const int* __restrict__ dst,
                          int* __restrict__ cursor, int* __restrict__ csr, int E)
{
    int e = blockIdx.x * 256 + threadIdx.x;
    if (e < E) {
        int d = dst[e];
        int pos = atomicAdd(&cursor[d], 1);
        csr[pos] = src[e];
    }
}

// ---------------- fused GIN layer v7: occupancy-maximized ----------------
// block = 128 threads (2 waves) = 16 nodes; sA only 8.4 KB LDS -> max resident
// waves (TLP experiment: does outstanding-miss capacity scale with waves?).
// Phase B: each wave computes the 16 rows x 64 cols half (4 accumulators).
template<int FINAL>
__global__ __launch_bounds__(128) void k_layer(
    const short* __restrict__ hqIn,
    const int* __restrict__ rstart, const int* __restrict__ csr,
    const float* __restrict__ invPtr, float invConst,
    const _Float16* __restrict__ WtHi, const _Float16* __restrict__ WtLo,
    const float* __restrict__ bias,
    const _Float16* __restrict__ WfHi, const _Float16* __restrict__ WfLo,
    float* __restrict__ outS,          // out + l*128, ld 768
    float* __restrict__ outF,          // out + 5*128 (FINAL only)
    short* __restrict__ hqOut,         // may be null
    int N)
{
    __shared__ float sA[16][132];      // 8.4 KB
    int t = threadIdx.x;
    float inv = invPtr ? invPtr[0] : invConst;
    int node0 = blockIdx.x * 16;

    // ---- phase A: aggregate 16 nodes (16 lanes/node, 8 nodes/pass, 2 passes) ----
    {
        int l16 = t & 15;
        int sg  = t >> 4;              // 0..7
        const shortx8* base = (const shortx8*)hqIn;
#pragma unroll
        for (int pass = 0; pass < 2; ++pass) {
            int nl = pass * 8 + sg;
            int node = node0 + nl;
            float* dstp = &sA[nl][l16 * 8];
            if (node < N) {
                int beg = rstart[node], end = rstart[node + 1];
                shortx8 sv = base[(size_t)node * 16 + l16];
                int acc[8];
#pragma unroll
                for (int j = 0; j < 8; ++j) acc[j] = (int)sv[j];
                int e = beg;
                if (e + 4 <= end) {
                    shortx8 b0 = base[(size_t)csr[e]     * 16 + l16];
                    shortx8 b1 = base[(size_t)csr[e + 1] * 16 + l16];
                    shortx8 b2 = base[(size_t)csr[e + 2] * 16 + l16];
                    shortx8 b3 = base[(size_t)csr[e + 3] * 16 + l16];
                    e += 4;
                    for (; e + 4 <= end; e += 4) {
                        shortx8 c0 = base[(size_t)csr[e]     * 16 + l16];
                        shortx8 c1 = base[(size_t)csr[e + 1] * 16 + l16];
                        shortx8 c2 = base[(size_t)csr[e + 2] * 16 + l16];
                        shortx8 c3 = base[(size_t)csr[e + 3] * 16 + l16];
#pragma unroll
                        for (int j = 0; j < 8; ++j)
                            acc[j] += ((int)b0[j] + (int)b1[j]) + ((int)b2[j] + (int)b3[j]);
                        b0 = c0; b1 = c1; b2 = c2; b3 = c3;
                    }
#pragma unroll
                    for (int j = 0; j < 8; ++j)
                        acc[j] += ((int)b0[j] + (int)b1[j]) + ((int)b2[j] + (int)b3[j]);
                }
                for (; e < end; ++e) {
                    shortx8 v0 = base[(size_t)csr[e] * 16 + l16];
#pragma unroll
                    for (int j = 0; j < 8; ++j) acc[j] += (int)v0[j];
                }
#pragma unroll
                for (int j = 0; j < 8; ++j) dstp[j] = acc[j] * inv;
            } else {
#pragma unroll
                for (int j = 0; j < 8; ++j) dstp[j] = 0.f;
            }
        }
    }
    __syncthreads();

    // ---- phase B: wave w computes 16 rows x cols [w*64, w*64+64) ----
    int wave = t >> 6;                 // 0..1
    int lane = t & 63;
    int colbase = wave * 64;
    int kg = (lane >> 4) * 8;
    int arow = lane & 15;

    half8 ahi[4], alo[4];
#pragma unroll
    for (int ks = 0; ks < 4; ++ks) {
        float4 f0 = *(const float4*)&sA[arow][ks * 32 + kg];
        float4 f1 = *(const float4*)&sA[arow][ks * 32 + kg + 4];
        float fv[8] = {f0.x, f0.y, f0.z, f0.w, f1.x, f1.y, f1.z, f1.w};
#pragma unroll
        for (int j = 0; j < 8; ++j) {
            _Float16 h = (_Float16)fv[j];
            ahi[ks][j] = h;
            alo[ks][j] = (_Float16)(fv[j] - (float)h);
        }
    }

    floatx4 acc[4];
#pragma unroll
    for (int nt = 0; nt < 4; ++nt) acc[nt] = (floatx4){0.f, 0.f, 0.f, 0.f};
#pragma unroll
    for (int nt = 0; nt < 4; ++nt) {
        int ncol = colbase + nt * 16 + (lane & 15);
#pragma unroll
        for (int ks = 0; ks < 4; ++ks) {
            half8 bhi = *(const half8*)(WtHi + (size_t)ncol * DIM + ks * 32 + kg);
            half8 blo = *(const half8*)(WtLo + (size_t)ncol * DIM + ks * 32 + kg);
            acc[nt] = __builtin_amdgcn_mfma_f32_16x16x32_f16(ahi[ks], bhi, acc[nt], 0, 0, 0);
            acc[nt] = __builtin_amdgcn_mfma_f32_16x16x32_f16(alo[ks], bhi, acc[nt], 0, 0, 0);
            acc[nt] = __builtin_amdgcn_mfma_f32_16x16x32_f16(ahi[ks], blo, acc[nt], 0, 0, 0);
        }
    }

    int rbase = (lane >> 4) * 4;
    float tv[4][4];
#pragma unroll
    for (int nt = 0; nt < 4; ++nt) {
        int col = colbase + nt * 16 + (lane & 15);
        float bv = bias[col];
#pragma unroll
        for (int j = 0; j < 4; ++j) {
            float tt = fast_tanh(acc[nt][j] + bv);
            tv[nt][j] = tt;
            int r = node0 + rbase + j;
            if (r < N) {
                __builtin_nontemporal_store(tt, &outS[(size_t)r * 768 + col]);
                if (hqOut) hqOut[(size_t)r * DIM + col] = quant(tt, SCALE_H);
            }
        }
    }

    if (FINAL) {
        __syncthreads();
#pragma unroll
        for (int nt = 0; nt < 4; ++nt) {
            int col = colbase + nt * 16 + (lane & 15);
#pragma unroll
            for (int j = 0; j < 4; ++j)
                sA[rbase + j][col] = tv[nt][j];
        }
        __syncthreads();

        half8 chi[4], clo[4];
#pragma unroll
        for (int ks = 0; ks < 4; ++ks) {
            float4 f0 = *(const float4*)&sA[arow][ks * 32 + kg];
            float4 f1 = *(const float4*)&sA[arow][ks * 32 + kg + 4];
            float fv[8] = {f0.x, f0.y, f0.z, f0.w, f1.x, f1.y, f1.z, f1.w};
#pragma unroll
            for (int j = 0; j < 8; ++j) {
                _Float16 h = (_Float16)fv[j];
                chi[ks][j] = h;
                clo[ks][j] = (_Float16)(fv[j] - (float)h);
            }
        }
        floatx4 ac2[4];
#pragma unroll
        for (int nt = 0; nt < 4; ++nt) ac2[nt] = (floatx4){0.f, 0.f, 0.f, 0.f};
#pragma unroll
        for (int nt = 0; nt < 4; ++nt) {
            int ncol = colbase + nt * 16 + (lane & 15);
#pragma unroll
            for (int ks = 0; ks < 4; ++ks) {
                half8 bhi = *(const half8*)(WfHi + (size_t)ncol * DIM + ks * 32 + kg);
                half8 blo = *(const half8*)(WfLo + (size_t)ncol * DIM + ks * 32 + kg);
                ac2[nt] = __builtin_amdgcn_mfma_f32_16x16x32_f16(chi[ks], bhi, ac2[nt], 0, 0, 0);
                ac2[nt] = __builtin_amdgcn_mfma_f32_16x16x32_f16(clo[ks], bhi, ac2[nt], 0, 0, 0);
                ac2[nt] = __builtin_amdgcn_mfma_f32_16x16x32_f16(chi[ks], blo, ac2[nt], 0, 0, 0);
            }
        }
#pragma unroll
        for (int nt = 0; nt < 4; ++nt) {
            int col = colbase + nt * 16 + (lane & 15);
#pragma unroll
            for (int j = 0; j < 4; ++j) {
                int r = node0 + rbase + j;
                if (r < N)
                    __builtin_nontemporal_store(fast_tanh(ac2[nt][j]), &outF[(size_t)r * 768 + col]);
            }
        }
    }
}

extern "C" void kernel_launch(void* const* d_in, const int* in_sizes, int n_in,
                              void* d_out, int out_size, void* d_ws, size_t ws_size,
                              hipStream_t stream)
{
    const float* x     = (const float*)d_in[0];
    const float* imp   = (const float*)d_in[1];
    const int*   eidx  = (const int*)d_in[2];
    const float* gamma = (const float*)d_in[3];
    const float* beta  = (const float*)d_in[4];
    const float* Wfc   = (const float*)d_in[5];
    const float* W[5]; const float* B[5];
    for (int i = 0; i < 5; ++i) {
        W[i] = (const float*)d_in[6 + 2 * i];
        B[i] = (const float*)d_in[7 + 2 * i];
    }
    float* out = (float*)d_out;

    const int N = in_sizes[0] / DIM;
    const int E = in_sizes[2] / 2;
    const int* src = eidx;
    const int* dst = eidx + E;

    char* ws = (char*)d_ws;
    size_t off = 0;
    auto alloc = [&](size_t b) -> char* {
        char* p = ws + off;
        off = (off + b + 255) & ~(size_t)255;
        return p;
    };
    short* hqA = (short*)alloc((size_t)N * DIM * 2);
    short* hqB = (short*)alloc((size_t)N * DIM * 2);
    _Float16* WtHi[6]; _Float16* WtLo[6];
    for (int i = 0; i < 6; ++i) {
        WtHi[i] = (_Float16*)alloc(DIM * DIM * 2);
        WtLo[i] = (_Float16*)alloc(DIM * DIM * 2);
    }
    int*   deg    = (int*)alloc((size_t)N * 4);
    int*   rstart = (int*)alloc((size_t)(N + 1) * 4);
    int*   cursor = (int*)alloc((size_t)N * 4);
    int*   csr    = (int*)alloc((size_t)E * 4);
    float* gsum   = (float*)alloc(128 * 4);
    float* gsq    = (float*)alloc(128 * 4);
    float* gmax   = (float*)alloc(128 * 4);
    float* scale  = (float*)alloc(128 * 4);
    float* shift  = (float*)alloc(128 * 4);
    float* q0     = (float*)alloc(2 * 4);
    int*   csum   = (int*)alloc(4096 * 4);

    hipMemsetAsync(gsum, 0, 128 * 4, stream);
    hipMemsetAsync(gsq,  0, 128 * 4, stream);
    hipMemsetAsync(gmax, 0, 128 * 4, stream);
    hipMemsetAsync(deg,  0, (size_t)N * 4, stream);

    // BN -> hq0 (int16, dynamic no-clip scale)
    k_stats<<<1024, 256, 0, stream>>>(x, imp, gsum, gsq, gmax, N);
    k_finalize<<<1, 128, 0, stream>>>(gsum, gsq, gmax, gamma, beta, scale, shift, q0, N);
    k_bn_quant<<<(N * 32 + 255) / 256, 256, 0, stream>>>(x, imp, scale, shift, q0, hqA, N * 32);

    // CSR
    k_hist<<<(E + 255) / 256, 256, 0, stream>>>(dst, deg, E);
    int nchunks = (N + 255) / 256;
    k_chunksum<<<nchunks, 256, 0, stream>>>(deg, csum, N);
    k_scanchunks<<<1, 512, 0, stream>>>(csum, rstart, nchunks, N);
    k_scanwithin<<<nchunks, 256, 0, stream>>>(deg, csum, rstart, cursor, N);
    k_scatter<<<(E + 255) / 256, 256, 0, stream>>>(src, dst, cursor, csr, E);

    // weights
    for (int i = 0; i < 5; ++i)
        k_wsplit<<<8, 256, 0, stream>>>(W[i], WtHi[i], WtLo[i]);
    k_wsplit<<<8, 256, 0, stream>>>(Wfc, WtHi[5], WtLo[5]);

    int grid = (N + 15) / 16;
    short* cur = hqA;
    short* nxt = hqB;
    for (int l = 0; l < 4; ++l) {
        k_layer<0><<<grid, 128, 0, stream>>>(cur, rstart, csr,
            (l == 0) ? (q0 + 1) : nullptr, INV_H,
            WtHi[l], WtLo[l], B[l], nullptr, nullptr,
            out + (size_t)l * DIM, nullptr, nxt, N);
        short* tmp = cur; cur = nxt; nxt = tmp;
    }
    // layer 5 + fused final FC
    k_layer<1><<<grid, 128, 0, stream>>>(cur, rstart, csr,
        nullptr, INV_H,
        WtHi[4], WtLo[4], B[4], WtHi[5], WtLo[5],
        out + (size_t)4 * DIM, out + (size_t)5 * DIM, nullptr, N);
}